// Round 6
// baseline (67.929 us; speedup 1.0000x reference)
//
#include <hip/hip_runtime.h>
#include <hip/hip_bf16.h>
#include <stdint.h>

#define DIM 1024
#define NTOK 8192

#define BM 128
#define BN 128
#define BK 64

typedef __attribute__((ext_vector_type(8))) short bf16x8;
typedef __attribute__((ext_vector_type(4))) float f32x4;

__device__ __forceinline__ unsigned short f2bf(float f) {
    union { float f; uint32_t u; } v; v.f = f;
    uint32_t u = v.u;
    u += 0x7FFFu + ((u >> 16) & 1u);   // round-to-nearest-even
    return (unsigned short)(u >> 16);
}

// async global->LDS, 16B per lane
#define GLOAD_LDS16(g, l)                                                \
    __builtin_amdgcn_global_load_lds(                                    \
        (const __attribute__((address_space(1))) void*)(g),              \
        (__attribute__((address_space(3))) void*)(l), 16, 0, 0)

// Closed-form uniform cubic B-spline (knots -2.2 + 0.55*i, i=0..8; weights s0..s4)
__device__ __forceinline__ float spline_eval(float xn, float s0, float s1,
                                             float s2, float s3, float s4) {
    const float xc = fminf(fmaxf(xn, -1.0f), 1.0f);
    const float u = (xc + 2.2f) * (1.0f / 0.55f);
    int j = (int)u;
    j = j < 2 ? 2 : (j > 5 ? 5 : j);
    const float t = u - (float)j;
    const float omt = 1.0f - t;
    const float t2 = t * t, t3 = t2 * t;
    const float w0 = omt * omt * omt * (1.0f / 6.0f);
    const float w1 = (3.0f * t3 - 6.0f * t2 + 4.0f) * (1.0f / 6.0f);
    const float w2 = (-3.0f * t3 + 3.0f * t2 + 3.0f * t + 1.0f) * (1.0f / 6.0f);
    const float w3 = t3 * (1.0f / 6.0f);
    float so;
    if (j == 2)      so = w1 * s0 + w2 * s1 + w3 * s2;
    else if (j == 3) so = w0 * s0 + w1 * s1 + w2 * s2 + w3 * s3;
    else if (j == 4) so = w0 * s1 + w1 * s2 + w2 * s3 + w3 * s4;
    else             so = w0 * s2 + w1 * s3 + w2 * s4;
    return so;
}

// ---------------------------------------------------------------------------
// Kernel 0: blocks [0,NTOK): RMSNorm row -> xnb (bf16) + r[row]
//           blocks [NTOK, NTOK+DIM): convert one W row f32 -> bf16
// ---------------------------------------------------------------------------
__global__ __launch_bounds__(256) void prep_kernel(
    const float* __restrict__ x, const float* __restrict__ nw,
    const float* __restrict__ W,
    unsigned short* __restrict__ xnb, unsigned short* __restrict__ Wb,
    float* __restrict__ rr)
{
    const int bid = blockIdx.x;
    const int t = threadIdx.x;

    if (bid >= NTOK) {                    // W conversion rows
        const size_t i = (size_t)(bid - NTOK) * (DIM / 4) + t;
        const float4 v = reinterpret_cast<const float4*>(W)[i];
        ushort4 o;
        o.x = f2bf(v.x); o.y = f2bf(v.y); o.z = f2bf(v.z); o.w = f2bf(v.w);
        reinterpret_cast<ushort4*>(Wb)[i] = o;
        return;
    }

    const int lane = t & 63, wid = t >> 6;
    const float4 v = reinterpret_cast<const float4*>(x + (size_t)bid * DIM)[t];

    float ssq = v.x * v.x + v.y * v.y + v.z * v.z + v.w * v.w;
    #pragma unroll
    for (int off = 32; off; off >>= 1) ssq += __shfl_xor(ssq, off, 64);

    __shared__ float red[4];
    if (lane == 0) red[wid] = ssq;
    __syncthreads();
    const float tot = red[0] + red[1] + red[2] + red[3];
    const float r = rsqrtf(tot * (1.0f / DIM) + 1e-6f);
    if (t == 0) rr[bid] = r;

    const float4 nwv = reinterpret_cast<const float4*>(nw)[t];
    ushort4 xb;
    xb.x = f2bf(v.x * r * nwv.x);
    xb.y = f2bf(v.y * r * nwv.y);
    xb.z = f2bf(v.z * r * nwv.z);
    xb.w = f2bf(v.w * r * nwv.w);
    reinterpret_cast<ushort4*>(xnb + (size_t)bid * DIM)[t] = xb;
}

// ---------------------------------------------------------------------------
// Kernel 1: bf16 MFMA GEMM C[n,d] = sum_k xn[n,k] * W[d,k], fused epilogue:
//   out[n,d] = x[n,d] + (C[n,d] + spline(x*r*nw, sw[d,:])) * gamma[d]
// 128x128 tile, BK=64 (16 iters), 4 waves (2x2), per-wave 64x64.
// A through LDS (ring-3, stage-1-ahead, counted vmcnt, raw s_barrier);
// B fragments DIRECT from global (W bf16 is L2-resident), reg double-buffer.
// A LDS swizzle: stage logical unit (t&7)^(row&7) at linear unit t&7;
// read at unit ((l>>4)^(l&7)) [s=1: ^4] -> even bank-quad spread.
// ---------------------------------------------------------------------------
__global__ __launch_bounds__(256, 2) void gemm_ep_kernel(
    const unsigned short* __restrict__ A,   // xn bf16 [NTOK][DIM]
    const unsigned short* __restrict__ B,   // W  bf16 [DIM][DIM]
    const float* __restrict__ x,
    const float* __restrict__ rrow,         // [NTOK]
    const float* __restrict__ nw,           // [DIM]
    const float* __restrict__ sw,           // [DIM][5]
    const float* __restrict__ gamma,
    float* __restrict__ out)
{
    __shared__ unsigned short SB[3 * 8192];          // 48 KB: 3 A-buffers (16KB)
    float* Cs = reinterpret_cast<float*>(SB);        // epilogue alias (33.8 KB)

    const int tid = threadIdx.x;
    const int lane = tid & 63, wid = tid >> 6;

    // XCD swizzle: xcd = bid&7 owns bm in [xcd*8, +8) x all 8 bn; consecutive
    // local ids share bn (B-fragment L1/L2 locality for co-resident blocks)
    const int bid = blockIdx.x;
    const int local = bid >> 3;
    const int bn = local >> 3;
    const int bm = (bid & 7) * 8 + (local & 7);

    const int wm = wid >> 1, wn = wid & 1;

    f32x4 acc[4][4] = {};

    // ---- A staging addressing (cooperative, 4 rounds of 32 rows) ----
    const int srow = tid >> 3;                                  // 0..31
    const int scol = ((tid & 7) ^ ((tid >> 3) & 7)) * 8;        // pre-swizzled unit
    const unsigned short* Ag = A + (size_t)(bm * BM + srow) * DIM + scol;
    const int oA = tid * 8;                                     // linear dest (shorts)

    // ---- B direct-from-global fragment pointers ----
    const unsigned short* bfp0 = B + (size_t)(bn * BN + wn * 64 +  0 + (lane & 15)) * DIM + (lane >> 4) * 8;
    const unsigned short* bfp1 = bfp0 + (size_t)16 * DIM;
    const unsigned short* bfp2 = bfp0 + (size_t)32 * DIM;
    const unsigned short* bfp3 = bfp0 + (size_t)48 * DIM;
    bf16x8 bfr[2][4][2];

    // ---- A fragment read offsets (swizzled) ----
    const int row0 = wm * 64 + (lane & 15);
    const int ku0 = (lane >> 4) ^ (lane & 7);
    const int oaf0 = row0 * 64 + ku0 * 8;           // s=0, shorts
    const int oaf1 = row0 * 64 + (ku0 ^ 4) * 8;     // s=1

#define STAGE_A(bi, kt) do {                                         \
        unsigned short* d_ = SB + (bi) * 8192 + oA;                  \
        const unsigned short* g_ = Ag + (size_t)(kt) * BK;           \
        GLOAD_LDS16(g_,            d_);                              \
        GLOAD_LDS16(g_ + 32 * DIM, d_ + 2048);                       \
        GLOAD_LDS16(g_ + 64 * DIM, d_ + 4096);                       \
        GLOAD_LDS16(g_ + 96 * DIM, d_ + 6144);                       \
    } while (0)

#define LOAD_B(st, kt) do {                                                          \
        bfr[st][0][0] = *reinterpret_cast<const bf16x8*>(bfp0 + (kt) * 64);          \
        bfr[st][0][1] = *reinterpret_cast<const bf16x8*>(bfp0 + (kt) * 64 + 32);     \
        bfr[st][1][0] = *reinterpret_cast<const bf16x8*>(bfp1 + (kt) * 64);          \
        bfr[st][1][1] = *reinterpret_cast<const bf16x8*>(bfp1 + (kt) * 64 + 32);     \
        bfr[st][2][0] = *reinterpret_cast<const bf16x8*>(bfp2 + (kt) * 64);          \
        bfr[st][2][1] = *reinterpret_cast<const bf16x8*>(bfp2 + (kt) * 64 + 32);     \
        bfr[st][3][0] = *reinterpret_cast<const bf16x8*>(bfp3 + (kt) * 64);          \
        bfr[st][3][1] = *reinterpret_cast<const bf16x8*>(bfp3 + (kt) * 64 + 32);     \
    } while (0)

#define COMP(bi, st) do {                                            \
        const unsigned short* sb_ = SB + (bi) * 8192;                \
        bf16x8 af0[4], af1[4];                                       \
        _Pragma("unroll")                                            \
        for (int i = 0; i < 4; ++i) {                                \
            af0[i] = *reinterpret_cast<const bf16x8*>(&sb_[oaf0 + i * 1024]); \
            af1[i] = *reinterpret_cast<const bf16x8*>(&sb_[oaf1 + i * 1024]); \
        }                                                            \
        _Pragma("unroll")                                            \
        for (int i = 0; i < 4; ++i)                                  \
            _Pragma("unroll")                                        \
            for (int j = 0; j < 4; ++j)                              \
                acc[i][j] = __builtin_amdgcn_mfma_f32_16x16x32_bf16( \
                    af0[i], bfr[st][j][0], acc[i][j], 0, 0, 0);      \
        _Pragma("unroll")                                            \
        for (int i = 0; i < 4; ++i)                                  \
            _Pragma("unroll")                                        \
            for (int j = 0; j < 4; ++j)                              \
                acc[i][j] = __builtin_amdgcn_mfma_f32_16x16x32_bf16( \
                    af1[i], bfr[st][j][1], acc[i][j], 0, 0, 0);      \
    } while (0)

#define STEP(kt, bc, bnx, sc, sn) do {                               \
        if ((kt) < 15) {                                             \
            STAGE_A(bnx, (kt) + 1);                                  \
            LOAD_B(sn, (kt) + 1);                                    \
            asm volatile("s_waitcnt vmcnt(12)" ::: "memory");        \
        } else {                                                     \
            asm volatile("s_waitcnt vmcnt(0)" ::: "memory");         \
        }                                                            \
        __builtin_amdgcn_s_barrier();                                \
        __builtin_amdgcn_sched_barrier(0);                           \
        COMP(bc, sc);                                                \
    } while (0)

    STAGE_A(0, 0);
    LOAD_B(0, 0);

    STEP( 0, 0, 1, 0, 1);
    STEP( 1, 1, 2, 1, 0);
    STEP( 2, 2, 0, 0, 1);
    STEP( 3, 0, 1, 1, 0);
    STEP( 4, 1, 2, 0, 1);
    STEP( 5, 2, 0, 1, 0);
    STEP( 6, 0, 1, 0, 1);
    STEP( 7, 1, 2, 1, 0);
    STEP( 8, 2, 0, 0, 1);
    STEP( 9, 0, 1, 1, 0);
    STEP(10, 1, 2, 0, 1);
    STEP(11, 2, 0, 1, 0);
    STEP(12, 0, 1, 0, 1);
    STEP(13, 1, 2, 1, 0);
    STEP(14, 2, 0, 0, 1);
    STEP(15, 0, 1, 1, 0);
    __syncthreads();

#undef STAGE_A
#undef LOAD_B
#undef COMP
#undef STEP

    // ---- fused epilogue: out = x + (C + spline(x*r*nw)) * gamma ----
    const int colg = bn * BN + (tid & 31) * 4;   // 4 consecutive output cols
    float sf[20];
    {
        const float4* swp = reinterpret_cast<const float4*>(sw + (size_t)colg * 5);
        #pragma unroll
        for (int q = 0; q < 5; ++q) {
            const float4 w4 = swp[q];
            sf[q * 4 + 0] = w4.x; sf[q * 4 + 1] = w4.y;
            sf[q * 4 + 2] = w4.z; sf[q * 4 + 3] = w4.w;
        }
    }
    const float4 gv  = *reinterpret_cast<const float4*>(gamma + colg);
    const float4 nwv = *reinterpret_cast<const float4*>(nw + colg);

    #pragma unroll
    for (int c = 0; c < 2; ++c) {
        if (wm == c) {
            #pragma unroll
            for (int i = 0; i < 4; ++i)
                #pragma unroll
                for (int j = 0; j < 4; ++j)
                    #pragma unroll
                    for (int r = 0; r < 4; ++r) {
                        const int lr = i * 16 + (lane >> 4) * 4 + r;
                        const int cc = wn * 64 + (lane & 15) + j * 16;
                        Cs[lr * 132 + cc] = acc[i][j][r];
                    }
        }
        __syncthreads();

        #pragma unroll
        for (int v = 0; v < 8; ++v) {
            const int lr = (tid >> 5) * 8 + v;       // 0..63
            const size_t grow = (size_t)(bm * BM + c * 64 + lr);
            const f32x4 cv = *reinterpret_cast<const f32x4*>(&Cs[lr * 132 + (tid & 31) * 4]);
            const float4 xv = *reinterpret_cast<const float4*>(x + grow * DIM + colg);
            const float rv = rrow[grow];
            float4 ov;
            ov.x = xv.x + (cv[0] + spline_eval(xv.x * rv * nwv.x, sf[0],  sf[1],  sf[2],  sf[3],  sf[4]))  * gv.x;
            ov.y = xv.y + (cv[1] + spline_eval(xv.y * rv * nwv.y, sf[5],  sf[6],  sf[7],  sf[8],  sf[9]))  * gv.y;
            ov.z = xv.z + (cv[2] + spline_eval(xv.z * rv * nwv.z, sf[10], sf[11], sf[12], sf[13], sf[14])) * gv.z;
            ov.w = xv.w + (cv[3] + spline_eval(xv.w * rv * nwv.w, sf[15], sf[16], sf[17], sf[18], sf[19])) * gv.w;
            *reinterpret_cast<float4*>(out + grow * DIM + colg) = ov;
        }
        if (c == 0) __syncthreads();
    }
}

// ---------------------------------------------------------------------------
extern "C" void kernel_launch(void* const* d_in, const int* in_sizes, int n_in,
                              void* d_out, int out_size, void* d_ws, size_t ws_size,
                              hipStream_t stream) {
    const float* x     = (const float*)d_in[0];
    const float* nw    = (const float*)d_in[1];
    const float* W     = (const float*)d_in[2];
    const float* sw    = (const float*)d_in[3];
    const float* gamma = (const float*)d_in[4];
    float* out = (float*)d_out;

    unsigned short* xnb = (unsigned short*)d_ws;              // 16 MB bf16 x_norm
    unsigned short* Wb  = xnb + (size_t)NTOK * DIM;           // 2 MB bf16 W
    float*          rr  = (float*)(Wb + (size_t)DIM * DIM);   // 32 KB row rsqrt

    prep_kernel<<<dim3(NTOK + DIM), 256, 0, stream>>>(x, nw, W, xnb, Wb, rr);
    gemm_ep_kernel<<<dim3((NTOK / BM) * (DIM / BN)), 256, 0, stream>>>(
        xnb, Wb, x, rr, nw, sw, gamma, out);
}

// Round 7
// 61.502 us; speedup vs baseline: 1.1045x; 1.1045x over previous
//
#include <hip/hip_runtime.h>
#include <hip/hip_bf16.h>
#include <stdint.h>

#define DIM 1024
#define NTOK 8192

#define BM 128
#define BN 256
#define BK 32

typedef __attribute__((ext_vector_type(8))) short bf16x8;
typedef __attribute__((ext_vector_type(4))) float f32x4;

__device__ __forceinline__ unsigned short f2bf(float f) {
    union { float f; uint32_t u; } v; v.f = f;
    uint32_t u = v.u;
    u += 0x7FFFu + ((u >> 16) & 1u);   // round-to-nearest-even
    return (unsigned short)(u >> 16);
}
__device__ __forceinline__ float bf2f(unsigned short h) {
    union { uint32_t u; float f; } v; v.u = ((uint32_t)h) << 16; return v.f;
}

// async global->LDS, 16B per lane (dest = wave base + lane*16, linear)
#define GLOAD_LDS16(g, l)                                                \
    __builtin_amdgcn_global_load_lds(                                    \
        (const __attribute__((address_space(1))) void*)(g),              \
        (__attribute__((address_space(3))) void*)(l), 16, 0, 0)

// Closed-form uniform cubic B-spline (knots -2.2 + 0.55*i; weights s0..s4)
__device__ __forceinline__ float spline_eval(float xn, float s0, float s1,
                                             float s2, float s3, float s4) {
    const float xc = fminf(fmaxf(xn, -1.0f), 1.0f);
    const float u = (xc + 2.2f) * (1.0f / 0.55f);
    int j = (int)u;
    j = j < 2 ? 2 : (j > 5 ? 5 : j);
    const float t = u - (float)j;
    const float omt = 1.0f - t;
    const float t2 = t * t, t3 = t2 * t;
    const float w0 = omt * omt * omt * (1.0f / 6.0f);
    const float w1 = (3.0f * t3 - 6.0f * t2 + 4.0f) * (1.0f / 6.0f);
    const float w2 = (-3.0f * t3 + 3.0f * t2 + 3.0f * t + 1.0f) * (1.0f / 6.0f);
    const float w3 = t3 * (1.0f / 6.0f);
    float so;
    if (j == 2)      so = w1 * s0 + w2 * s1 + w3 * s2;
    else if (j == 3) so = w0 * s0 + w1 * s1 + w2 * s2 + w3 * s3;
    else if (j == 4) so = w0 * s1 + w1 * s2 + w2 * s3 + w3 * s4;
    else             so = w0 * s2 + w1 * s3 + w2 * s4;
    return so;
}

// ---------------------------------------------------------------------------
// Kernel 0: blocks [0,NTOK): RMSNorm row -> xnb (bf16)
//           blocks [NTOK, NTOK+DIM): convert one W row f32 -> bf16
// ---------------------------------------------------------------------------
__global__ __launch_bounds__(256) void prep_kernel(
    const float* __restrict__ x, const float* __restrict__ nw,
    const float* __restrict__ W,
    unsigned short* __restrict__ xnb, unsigned short* __restrict__ Wb)
{
    const int bid = blockIdx.x;
    const int t = threadIdx.x;

    if (bid >= NTOK) {                    // W conversion rows
        const size_t i = (size_t)(bid - NTOK) * (DIM / 4) + t;
        const float4 v = reinterpret_cast<const float4*>(W)[i];
        ushort4 o;
        o.x = f2bf(v.x); o.y = f2bf(v.y); o.z = f2bf(v.z); o.w = f2bf(v.w);
        reinterpret_cast<ushort4*>(Wb)[i] = o;
        return;
    }

    const int lane = t & 63, wid = t >> 6;
    const float4 v = reinterpret_cast<const float4*>(x + (size_t)bid * DIM)[t];

    float ssq = v.x * v.x + v.y * v.y + v.z * v.z + v.w * v.w;
    #pragma unroll
    for (int off = 32; off; off >>= 1) ssq += __shfl_xor(ssq, off, 64);

    __shared__ float red[4];
    if (lane == 0) red[wid] = ssq;
    __syncthreads();
    const float tot = red[0] + red[1] + red[2] + red[3];
    const float r = rsqrtf(tot * (1.0f / DIM) + 1e-6f);

    const float4 nwv = reinterpret_cast<const float4*>(nw)[t];
    ushort4 xb;
    xb.x = f2bf(v.x * r * nwv.x);
    xb.y = f2bf(v.y * r * nwv.y);
    xb.z = f2bf(v.z * r * nwv.z);
    xb.w = f2bf(v.w * r * nwv.w);
    reinterpret_cast<ushort4*>(xnb + (size_t)bid * DIM)[t] = xb;
}

// ---------------------------------------------------------------------------
// Kernel 1: bf16 MFMA GEMM C[n,d] = sum_k xn[n,k] * W[d,k], fused epilogue:
//   out[n,d] = x[n,d] + (C[n,d] + spline(xn[n,d], sw[d,:])) * gamma[d]
// BM=128 x BN=256 block, 4 waves wn-split, PER-WAVE 128x64 (8x4 frags):
// 2.67 MFMA per ds_read_b128 vs 2.0 at 64x64 -- the kernel is LDS-BW-bound
// (r3/r4 depth-null, r5 ratio-down-worse, r6 L2-shift-worse).
// Grid 256 = 1 block/CU. 4-buffer ring (24KB each, 96KB), counted vmcnt(12),
// raw s_barrier -- r4's verified schedule scaled to 6 loads/stage.
// Same verified LDS swizzle: stage global unit (t&3)^((t>>3)&3) at linear
// dest; read unit (lane>>4)^((lane>>1)&3).
// ---------------------------------------------------------------------------
__global__ __launch_bounds__(256, 1) void gemm_ep_kernel(
    const unsigned short* __restrict__ A,   // xn bf16 [NTOK][DIM]
    const unsigned short* __restrict__ B,   // W  bf16 [DIM][DIM]
    const float* __restrict__ x,
    const float* __restrict__ sw,           // [DIM][5]
    const float* __restrict__ gamma,
    float* __restrict__ out)
{
    __shared__ unsigned short SB[4 * 12288];     // 96 KB: 4 x (A 8KB + B 16KB)
    float* Cs = reinterpret_cast<float*>(SB);    // epilogue alias (64x260 = 66.6KB)

    const int tid = threadIdx.x;
    const int lane = tid & 63, wn = tid >> 6;    // wave = output cols wn*64..+63

    // XCD swizzle: 256 blocks, xcd = bid&7 owns 8 bm panels x all 4 bn
    const int bid = blockIdx.x;
    const int local = bid >> 3;                  // 0..31
    const int bm = (bid & 7) * 8 + (local >> 2); // 0..63
    const int bn = local & 3;                    // 0..3

    f32x4 acc[8][4] = {};

    // ---- staging addressing ----
    const int srow = tid >> 2;                                  // 0..63
    const int scol = ((tid & 3) ^ ((tid >> 3) & 3)) * 8;        // pre-swizzled unit
    const unsigned short* Ag = A + (size_t)(bm * BM + srow) * DIM + scol;
    const unsigned short* Bg = B + (size_t)(bn * BN + srow) * DIM + scol;
    const int oA = tid * 8;                     // shorts; A rows 0..127 -> [0,4096)
    const int oB = 4096 + tid * 8;              // B rows 0..255 -> [4096,12288)

    // ---- fragment read offsets (swizzled, verified r4) ----
    const int arow = lane & 15;
    const int brow = (lane & 15);               // within wave's 64-row B slice
    const int bbase = 4096 + (wn * 64) * 32;    // B region + wave col offset
    const int kofs = ((lane >> 4) ^ ((lane >> 1) & 3)) * 8;

#define STAGE(bi, kt) do {                                           \
        unsigned short* sb_ = SB + (bi) * 12288;                     \
        const unsigned short* a_ = Ag + (size_t)(kt) * BK;           \
        const unsigned short* b_ = Bg + (size_t)(kt) * BK;           \
        GLOAD_LDS16(a_,             sb_ + oA);                       \
        GLOAD_LDS16(a_ + 64 * DIM,  sb_ + oA + 2048);                \
        GLOAD_LDS16(b_,             sb_ + oB);                       \
        GLOAD_LDS16(b_ + 64 * DIM,  sb_ + oB + 2048);                \
        GLOAD_LDS16(b_ + 128 * DIM, sb_ + oB + 4096);                \
        GLOAD_LDS16(b_ + 192 * DIM, sb_ + oB + 6144);                \
    } while (0)

#define COMP(bi) do {                                                \
        const unsigned short* sb_ = SB + (bi) * 12288;               \
        bf16x8 af[8], bfv[4];                                        \
        _Pragma("unroll")                                            \
        for (int i = 0; i < 8; ++i)                                  \
            af[i] = *reinterpret_cast<const bf16x8*>(                \
                &sb_[(arow + i * 16) * 32 + kofs]);                  \
        _Pragma("unroll")                                            \
        for (int j = 0; j < 4; ++j)                                  \
            bfv[j] = *reinterpret_cast<const bf16x8*>(               \
                &sb_[bbase + (brow + j * 16) * 32 + kofs]);          \
        _Pragma("unroll")                                            \
        for (int i = 0; i < 8; ++i)                                  \
            _Pragma("unroll")                                        \
            for (int j = 0; j < 4; ++j)                              \
                acc[i][j] = __builtin_amdgcn_mfma_f32_16x16x32_bf16( \
                    af[i], bfv[j], acc[i][j], 0, 0, 0);              \
    } while (0)

#define W12 asm volatile("s_waitcnt vmcnt(12)" ::: "memory")
#define W6  asm volatile("s_waitcnt vmcnt(6)"  ::: "memory")
#define W0  asm volatile("s_waitcnt vmcnt(0)"  ::: "memory")
#define BAR __builtin_amdgcn_s_barrier()

    STAGE(0, 0);
    STAGE(1, 1);
    #pragma unroll 1
    for (int k4 = 0; k4 < 28; k4 += 4) {
        STAGE(2, k4 + 2); W12; BAR; COMP(0);
        STAGE(3, k4 + 3); W12; BAR; COMP(1);
        STAGE(0, k4 + 4); W12; BAR; COMP(2);
        STAGE(1, k4 + 5); W12; BAR; COMP(3);
    }
    STAGE(2, 30); W12; BAR; COMP(0);   // iter 28
    STAGE(3, 31); W12; BAR; COMP(1);   // iter 29
    W6; BAR; COMP(2);                  // iter 30
    W0; BAR; COMP(3);                  // iter 31
    __syncthreads();

#undef STAGE
#undef COMP
#undef W12
#undef W6
#undef W0
#undef BAR

    // ---- fused epilogue: 2 chunks of 64 rows x 256 cols through Cs ----
    const int colg = bn * BN + (tid & 63) * 4;   // 4 consecutive output cols
    float sf[20];
    {
        const float4* swp = reinterpret_cast<const float4*>(sw + (size_t)colg * 5);
        #pragma unroll
        for (int q = 0; q < 5; ++q) {
            const float4 w4 = swp[q];
            sf[q * 4 + 0] = w4.x; sf[q * 4 + 1] = w4.y;
            sf[q * 4 + 2] = w4.z; sf[q * 4 + 3] = w4.w;
        }
    }
    const float4 gv = *reinterpret_cast<const float4*>(gamma + colg);

    #pragma unroll
    for (int c = 0; c < 2; ++c) {
        // all 4 waves write their disjoint 64-col slices of rows [c*64, +64)
        #pragma unroll
        for (int i = 0; i < 4; ++i)
            #pragma unroll
            for (int j = 0; j < 4; ++j)
                #pragma unroll
                for (int r = 0; r < 4; ++r) {
                    const int lr = i * 16 + (lane >> 4) * 4 + r;
                    const int cc = wn * 64 + j * 16 + (lane & 15);
                    Cs[lr * 260 + cc] = acc[c * 4 + i][j][r];
                }
        __syncthreads();

        #pragma unroll
        for (int v = 0; v < 16; ++v) {
            const int lr = (tid >> 6) * 16 + v;          // 0..63
            const size_t grow = (size_t)(bm * BM + c * 64 + lr);
            const f32x4 cv = *reinterpret_cast<const f32x4*>(&Cs[lr * 260 + (tid & 63) * 4]);
            const float4 xv = *reinterpret_cast<const float4*>(x + grow * DIM + colg);
            const ushort4 xnv = *reinterpret_cast<const ushort4*>(A + grow * DIM + colg);
            float4 ov;
            ov.x = xv.x + (cv[0] + spline_eval(bf2f(xnv.x), sf[0],  sf[1],  sf[2],  sf[3],  sf[4]))  * gv.x;
            ov.y = xv.y + (cv[1] + spline_eval(bf2f(xnv.y), sf[5],  sf[6],  sf[7],  sf[8],  sf[9]))  * gv.y;
            ov.z = xv.z + (cv[2] + spline_eval(bf2f(xnv.z), sf[10], sf[11], sf[12], sf[13], sf[14])) * gv.z;
            ov.w = xv.w + (cv[3] + spline_eval(bf2f(xnv.w), sf[15], sf[16], sf[17], sf[18], sf[19])) * gv.w;
            *reinterpret_cast<float4*>(out + grow * DIM + colg) = ov;
        }
        if (c == 0) __syncthreads();
    }
}

// ---------------------------------------------------------------------------
extern "C" void kernel_launch(void* const* d_in, const int* in_sizes, int n_in,
                              void* d_out, int out_size, void* d_ws, size_t ws_size,
                              hipStream_t stream) {
    const float* x     = (const float*)d_in[0];
    const float* nw    = (const float*)d_in[1];
    const float* W     = (const float*)d_in[2];
    const float* sw    = (const float*)d_in[3];
    const float* gamma = (const float*)d_in[4];
    float* out = (float*)d_out;

    unsigned short* xnb = (unsigned short*)d_ws;              // 16 MB bf16 x_norm
    unsigned short* Wb  = xnb + (size_t)NTOK * DIM;           // 2 MB bf16 W

    prep_kernel<<<dim3(NTOK + DIM), 256, 0, stream>>>(x, nw, W, xnb, Wb);
    gemm_ep_kernel<<<dim3((NTOK / BM) * (DIM / BN)), 256, 0, stream>>>(
        xnb, Wb, x, sw, gamma, out);
}

// Round 8
// 51.468 us; speedup vs baseline: 1.3198x; 1.1949x over previous
//
#include <hip/hip_runtime.h>
#include <hip/hip_bf16.h>
#include <stdint.h>

#define DIM 1024
#define NTOK 8192

#define BM 128
#define BN 128
#define BK 32

typedef __attribute__((ext_vector_type(8))) short bf16x8;
typedef __attribute__((ext_vector_type(4))) float f32x4;

__device__ __forceinline__ unsigned short f2bf(float f) {
    union { float f; uint32_t u; } v; v.f = f;
    uint32_t u = v.u;
    u += 0x7FFFu + ((u >> 16) & 1u);   // round-to-nearest-even
    return (unsigned short)(u >> 16);
}

// async global->LDS, 16B per lane (dest = wave base + lane*16, linear)
#define GLOAD_LDS16(g, l)                                                \
    __builtin_amdgcn_global_load_lds(                                    \
        (const __attribute__((address_space(1))) void*)(g),              \
        (__attribute__((address_space(3))) void*)(l), 16, 0, 0)

// Closed-form uniform cubic B-spline (knots -2.2 + 0.55*i; weights s0..s4)
__device__ __forceinline__ float spline_eval(float xn, float s0, float s1,
                                             float s2, float s3, float s4) {
    const float xc = fminf(fmaxf(xn, -1.0f), 1.0f);
    const float u = (xc + 2.2f) * (1.0f / 0.55f);
    int j = (int)u;
    j = j < 2 ? 2 : (j > 5 ? 5 : j);
    const float t = u - (float)j;
    const float omt = 1.0f - t;
    const float t2 = t * t, t3 = t2 * t;
    const float w0 = omt * omt * omt * (1.0f / 6.0f);
    const float w1 = (3.0f * t3 - 6.0f * t2 + 4.0f) * (1.0f / 6.0f);
    const float w2 = (-3.0f * t3 + 3.0f * t2 + 3.0f * t + 1.0f) * (1.0f / 6.0f);
    const float w3 = t3 * (1.0f / 6.0f);
    float so;
    if (j == 2)      so = w1 * s0 + w2 * s1 + w3 * s2;
    else if (j == 3) so = w0 * s0 + w1 * s1 + w2 * s2 + w3 * s3;
    else if (j == 4) so = w0 * s1 + w1 * s2 + w2 * s3 + w3 * s4;
    else             so = w0 * s2 + w1 * s3 + w2 * s4;
    return so;
}

// ---------------------------------------------------------------------------
// Kernel 0: blocks [0,NTOK): RMSNorm row -> xnb (bf16) + rr[row]
//           blocks [NTOK, NTOK+DIM): convert one W row f32 -> bf16
// ---------------------------------------------------------------------------
__global__ __launch_bounds__(256) void prep_kernel(
    const float* __restrict__ x, const float* __restrict__ nw,
    const float* __restrict__ W,
    unsigned short* __restrict__ xnb, unsigned short* __restrict__ Wb,
    float* __restrict__ rr)
{
    const int bid = blockIdx.x;
    const int t = threadIdx.x;

    if (bid >= NTOK) {                    // W conversion rows
        const size_t i = (size_t)(bid - NTOK) * (DIM / 4) + t;
        const float4 v = reinterpret_cast<const float4*>(W)[i];
        ushort4 o;
        o.x = f2bf(v.x); o.y = f2bf(v.y); o.z = f2bf(v.z); o.w = f2bf(v.w);
        reinterpret_cast<ushort4*>(Wb)[i] = o;
        return;
    }

    const int lane = t & 63, wid = t >> 6;
    const float4 v = reinterpret_cast<const float4*>(x + (size_t)bid * DIM)[t];

    float ssq = v.x * v.x + v.y * v.y + v.z * v.z + v.w * v.w;
    #pragma unroll
    for (int off = 32; off; off >>= 1) ssq += __shfl_xor(ssq, off, 64);

    __shared__ float red[4];
    if (lane == 0) red[wid] = ssq;
    __syncthreads();
    const float tot = red[0] + red[1] + red[2] + red[3];
    const float r = rsqrtf(tot * (1.0f / DIM) + 1e-6f);
    if (t == 0) rr[bid] = r;

    const float4 nwv = reinterpret_cast<const float4*>(nw)[t];
    ushort4 xb;
    xb.x = f2bf(v.x * r * nwv.x);
    xb.y = f2bf(v.y * r * nwv.y);
    xb.z = f2bf(v.z * r * nwv.z);
    xb.w = f2bf(v.w * r * nwv.w);
    reinterpret_cast<ushort4*>(xnb + (size_t)bid * DIM)[t] = xb;
}

// ---------------------------------------------------------------------------
// Kernel 1: bf16 MFMA GEMM C[n,d] = sum_k xn[n,k] * W[d,k], fused epilogue:
//   out[n,d] = x[n,d] + (C[n,d] + spline(x*r*nw, sw[d,:])) * gamma[d]
// r4 geometry (128x128, BK=32, 4 waves 2x2, counted vmcnt, raw s_barrier)
// with ring-3 staging (48 KB) -> 3 blocks/CU (12 waves) for latency-gap TLP.
// Race-free: STAGE(kt+2) issued post-COMP(kt); its buffer's previous reader
// COMP(kt-1) is separated by BAR(kt). W4 ensures stage kt landed (only
// stage kt+1's 4 loads may remain outstanding).
// ---------------------------------------------------------------------------
__global__ __launch_bounds__(256, 3) void gemm_ep_kernel(
    const unsigned short* __restrict__ A,   // xn bf16 [NTOK][DIM]
    const unsigned short* __restrict__ B,   // W  bf16 [DIM][DIM]
    const float* __restrict__ x,
    const float* __restrict__ rrow,         // [NTOK]
    const float* __restrict__ nw,           // [DIM]
    const float* __restrict__ sw,           // [DIM][5]
    const float* __restrict__ gamma,
    float* __restrict__ out)
{
    __shared__ unsigned short SB[3 * 8192];          // 48 KB: ring-3 staging
    float* Cs = reinterpret_cast<float*>(SB);        // epilogue alias (33.8 KB)

    const int tid = threadIdx.x;
    const int lane = tid & 63, wid = tid >> 6;

    // XCD swizzle: 512 blocks, xcd = bid&7 gets 8 bm panels x all 8 bn
    const int bid = blockIdx.x;
    const int swz = (bid & 7) * 64 + (bid >> 3);
    const int bm = swz >> 3, bn = swz & 7;

    const int wm = wid >> 1, wn = wid & 1;

    f32x4 acc[4][4] = {};

    // staging: LDS dest linear (base + lane*16B); global source pre-swizzled
    const int srow = wid * 16 + (lane >> 2);
    const int scol = ((lane & 3) ^ ((lane >> 3) & 3)) * 8;    // swizzled source unit
    const unsigned short* Ag = A + ((size_t)(bm * BM + srow)) * DIM + scol;
    const unsigned short* Bg = B + ((size_t)(bn * BN + srow)) * DIM + scol;
    const int oA0 = srow * BK + (lane & 3) * 8;               // linear dest
    const int oA1 = (srow + 64) * BK + (lane & 3) * 8;
    const int oB0 = 4096 + srow * BK + (lane & 3) * 8;
    const int oB1 = 4096 + (srow + 64) * BK + (lane & 3) * 8;

    const int arow = wm * 64 + (lane & 15);
    const int brow = wn * 64 + (lane & 15);
    // swizzled read: global k-unit (lane>>4) lives at LDS unit ^ ((row>>1)&3)
    const int kofs = (((lane >> 4) ^ ((lane >> 1) & 3))) * 8;

#define STAGE(bi, kt) do {                                           \
        unsigned short* sb_ = SB + (bi) * 8192;                      \
        const unsigned short* a0_ = Ag + (size_t)(kt) * BK;          \
        const unsigned short* b0_ = Bg + (size_t)(kt) * BK;          \
        GLOAD_LDS16(a0_,            sb_ + oA0);                      \
        GLOAD_LDS16(a0_ + 64 * DIM, sb_ + oA1);                      \
        GLOAD_LDS16(b0_,            sb_ + oB0);                      \
        GLOAD_LDS16(b0_ + 64 * DIM, sb_ + oB1);                      \
    } while (0)

#define COMP(bi) do {                                                \
        const unsigned short* sb_ = SB + (bi) * 8192;                \
        bf16x8 af[4], bfr[4];                                        \
        _Pragma("unroll")                                            \
        for (int i = 0; i < 4; ++i)                                  \
            af[i] = *reinterpret_cast<const bf16x8*>(                \
                &sb_[(arow + i * 16) * BK + kofs]);                  \
        _Pragma("unroll")                                            \
        for (int j = 0; j < 4; ++j)                                  \
            bfr[j] = *reinterpret_cast<const bf16x8*>(               \
                &sb_[4096 + (brow + j * 16) * BK + kofs]);           \
        _Pragma("unroll")                                            \
        for (int i = 0; i < 4; ++i)                                  \
            _Pragma("unroll")                                        \
            for (int j = 0; j < 4; ++j)                              \
                acc[i][j] = __builtin_amdgcn_mfma_f32_16x16x32_bf16( \
                    af[i], bfr[j], acc[i][j], 0, 0, 0);              \
    } while (0)

#define W4  asm volatile("s_waitcnt vmcnt(4)" ::: "memory")
#define W0  asm volatile("s_waitcnt vmcnt(0)" ::: "memory")
#define BAR __builtin_amdgcn_s_barrier()

    STAGE(0, 0);
    STAGE(1, 1);
    // iters 0..29 in groups of 3 (buffer indices compile-time constant)
    #pragma unroll 1
    for (int g = 0; g < 10; ++g) {
        const int kt = g * 3;
        W4; BAR; COMP(0); STAGE(2, kt + 2);
        W4; BAR; COMP(1); STAGE(0, kt + 3);
        W4; BAR; COMP(2); STAGE(1, kt + 4);
    }
    // note: group g=9 staged tiles 29,30,31; nothing left to stage
    W4; BAR; COMP(0);    // kt=30 (buf 30%3=0)
    W0; BAR; COMP(1);    // kt=31 (buf 31%3=1)
    __syncthreads();

#undef STAGE
#undef COMP
#undef W4
#undef W0
#undef BAR

    // ---- fused epilogue: out = x + (C + spline(x*r*nw)) * gamma ----
    const int colg = bn * BN + (tid & 31) * 4;   // 4 consecutive output cols
    float sf[20];
    {
        const float4* swp = reinterpret_cast<const float4*>(sw + (size_t)colg * 5);
        #pragma unroll
        for (int q = 0; q < 5; ++q) {
            const float4 w4 = swp[q];
            sf[q * 4 + 0] = w4.x; sf[q * 4 + 1] = w4.y;
            sf[q * 4 + 2] = w4.z; sf[q * 4 + 3] = w4.w;
        }
    }
    const float4 gv  = *reinterpret_cast<const float4*>(gamma + colg);
    const float4 nwv = *reinterpret_cast<const float4*>(nw + colg);

    #pragma unroll
    for (int c = 0; c < 2; ++c) {
        if (wm == c) {
            #pragma unroll
            for (int i = 0; i < 4; ++i)
                #pragma unroll
                for (int j = 0; j < 4; ++j)
                    #pragma unroll
                    for (int r = 0; r < 4; ++r) {
                        const int lr = i * 16 + (lane >> 4) * 4 + r;
                        const int cc = wn * 64 + (lane & 15) + j * 16;
                        Cs[lr * 132 + cc] = acc[i][j][r];
                    }
        }
        __syncthreads();

        #pragma unroll
        for (int v = 0; v < 8; ++v) {
            const int lr = (tid >> 5) * 8 + v;       // 0..63
            const size_t grow = (size_t)(bm * BM + c * 64 + lr);
            const f32x4 cv = *reinterpret_cast<const f32x4*>(&Cs[lr * 132 + (tid & 31) * 4]);
            const float4 xv = *reinterpret_cast<const float4*>(x + grow * DIM + colg);
            const float rv = rrow[grow];
            float4 ov;
            ov.x = xv.x + (cv[0] + spline_eval(xv.x * rv * nwv.x, sf[0],  sf[1],  sf[2],  sf[3],  sf[4]))  * gv.x;
            ov.y = xv.y + (cv[1] + spline_eval(xv.y * rv * nwv.y, sf[5],  sf[6],  sf[7],  sf[8],  sf[9]))  * gv.y;
            ov.z = xv.z + (cv[2] + spline_eval(xv.z * rv * nwv.z, sf[10], sf[11], sf[12], sf[13], sf[14])) * gv.z;
            ov.w = xv.w + (cv[3] + spline_eval(xv.w * rv * nwv.w, sf[15], sf[16], sf[17], sf[18], sf[19])) * gv.w;
            *reinterpret_cast<float4*>(out + grow * DIM + colg) = ov;
        }
        if (c == 0) __syncthreads();
    }
}

// ---------------------------------------------------------------------------
extern "C" void kernel_launch(void* const* d_in, const int* in_sizes, int n_in,
                              void* d_out, int out_size, void* d_ws, size_t ws_size,
                              hipStream_t stream) {
    const float* x     = (const float*)d_in[0];
    const float* nw    = (const float*)d_in[1];
    const float* W     = (const float*)d_in[2];
    const float* sw    = (const float*)d_in[3];
    const float* gamma = (const float*)d_in[4];
    float* out = (float*)d_out;

    unsigned short* xnb = (unsigned short*)d_ws;              // 16 MB bf16 x_norm
    unsigned short* Wb  = xnb + (size_t)NTOK * DIM;           // 2 MB bf16 W
    float*          rr  = (float*)(Wb + (size_t)DIM * DIM);   // 32 KB row rsqrt

    prep_kernel<<<dim3(NTOK + DIM), 256, 0, stream>>>(x, nw, W, xnb, Wb, rr);
    gemm_ep_kernel<<<dim3((NTOK / BM) * (DIM / BN)), 256, 0, stream>>>(
        xnb, Wb, x, rr, nw, sw, gamma, out);
}

// Round 9
// 42.128 us; speedup vs baseline: 1.6124x; 1.2217x over previous
//
#include <hip/hip_runtime.h>
#include <hip/hip_bf16.h>
#include <stdint.h>

#define DIM 1024
#define NTOK 8192

#define BM 128
#define BN 128
#define BK 64            // fp8: 64 bytes per row-tile (same 64B geometry as r4)

typedef unsigned char uchar;
typedef __attribute__((ext_vector_type(4)))  int   i32x4;
typedef __attribute__((ext_vector_type(8)))  int   i32x8;
typedef __attribute__((ext_vector_type(4)))  float f32x4;
typedef __attribute__((ext_vector_type(16))) float f32x16;

// async global->LDS, 16B per lane (dest = wave base + lane*16, linear)
#define GLOAD_LDS16(g, l)                                                \
    __builtin_amdgcn_global_load_lds(                                    \
        (const __attribute__((address_space(1))) void*)(g),              \
        (__attribute__((address_space(3))) void*)(l), 16, 0, 0)

// Closed-form uniform cubic B-spline (knots -2.2 + 0.55*i; weights s0..s4)
__device__ __forceinline__ float spline_eval(float xn, float s0, float s1,
                                             float s2, float s3, float s4) {
    const float xc = fminf(fmaxf(xn, -1.0f), 1.0f);
    const float u = (xc + 2.2f) * (1.0f / 0.55f);
    int j = (int)u;
    j = j < 2 ? 2 : (j > 5 ? 5 : j);
    const float t = u - (float)j;
    const float omt = 1.0f - t;
    const float t2 = t * t, t3 = t2 * t;
    const float w0 = omt * omt * omt * (1.0f / 6.0f);
    const float w1 = (3.0f * t3 - 6.0f * t2 + 4.0f) * (1.0f / 6.0f);
    const float w2 = (-3.0f * t3 + 3.0f * t2 + 3.0f * t + 1.0f) * (1.0f / 6.0f);
    const float w3 = t3 * (1.0f / 6.0f);
    float so;
    if (j == 2)      so = w1 * s0 + w2 * s1 + w3 * s2;
    else if (j == 3) so = w0 * s0 + w1 * s1 + w2 * s2 + w3 * s3;
    else if (j == 4) so = w0 * s1 + w1 * s2 + w2 * s3 + w3 * s4;
    else             so = w0 * s2 + w1 * s3 + w2 * s4;
    return so;
}

__device__ __forceinline__ int pack_fp8x4(float a, float b, float c, float d) {
    int p = __builtin_amdgcn_cvt_pk_fp8_f32(a, b, 0, false);   // bytes 0,1
    p = __builtin_amdgcn_cvt_pk_fp8_f32(c, d, p, true);        // bytes 2,3
    return p;
}

// ---------------------------------------------------------------------------
// Kernel 0: blocks [0,NTOK): RMSNorm row -> xn8 (fp8 e4m3) + rr[row]
//           blocks [NTOK, NTOK+DIM): convert one W row f32 -> fp8
// ---------------------------------------------------------------------------
__global__ __launch_bounds__(256) void prep_kernel(
    const float* __restrict__ x, const float* __restrict__ nw,
    const float* __restrict__ W,
    uchar* __restrict__ xn8, uchar* __restrict__ W8,
    float* __restrict__ rr)
{
    const int bid = blockIdx.x;
    const int t = threadIdx.x;

    if (bid >= NTOK) {                    // W conversion rows
        const size_t i = (size_t)(bid - NTOK) * (DIM / 4) + t;
        const float4 v = reinterpret_cast<const float4*>(W)[i];
        reinterpret_cast<int*>(W8)[i] = pack_fp8x4(v.x, v.y, v.z, v.w);
        return;
    }

    const int lane = t & 63, wid = t >> 6;
    const float4 v = reinterpret_cast<const float4*>(x + (size_t)bid * DIM)[t];

    float ssq = v.x * v.x + v.y * v.y + v.z * v.z + v.w * v.w;
    #pragma unroll
    for (int off = 32; off; off >>= 1) ssq += __shfl_xor(ssq, off, 64);

    __shared__ float red[4];
    if (lane == 0) red[wid] = ssq;
    __syncthreads();
    const float tot = red[0] + red[1] + red[2] + red[3];
    const float r = rsqrtf(tot * (1.0f / DIM) + 1e-6f);
    if (t == 0) rr[bid] = r;

    const float4 nwv = reinterpret_cast<const float4*>(nw)[t];
    reinterpret_cast<int*>(xn8 + (size_t)bid * DIM)[t] =
        pack_fp8x4(v.x * r * nwv.x, v.y * r * nwv.y,
                   v.z * r * nwv.z, v.w * r * nwv.w);
}

// ---------------------------------------------------------------------------
// Kernel 1: MX-fp8 MFMA GEMM C[n,d] = sum_k xn[n,k] * W[d,k], fused epilogue:
//   out[n,d] = x[n,d] + (C[n,d] + spline(x*r*nw, sw[d,:])) * gamma[d]
// r4's exact proven structure, dtype-ported: 128x128 tile, BK=64 (16 iters),
// 4 waves 2x2, per-wave 64x64 = 2x2 frags of mfma_scale_32x32x64_f8f6f4
// (scales = 1.0). Ring-4 staging (4 x 16KB), counted vmcnt(8), raw s_barrier,
// STAGE->W8->BAR->COMP order. Rows are 64B (= r4 geometry), so r4's verified
// swizzle pair transfers: source unit (t&3)^((t>>3)&3), read XOR (l>>1)&3.
// ---------------------------------------------------------------------------
__global__ __launch_bounds__(256, 2) void gemm_ep_kernel(
    const uchar* __restrict__ A,   // xn fp8 [NTOK][DIM]
    const uchar* __restrict__ B,   // W  fp8 [DIM][DIM]
    const float* __restrict__ x,
    const float* __restrict__ rrow,         // [NTOK]
    const float* __restrict__ nw,           // [DIM]
    const float* __restrict__ sw,           // [DIM][5]
    const float* __restrict__ gamma,
    float* __restrict__ out)
{
    __shared__ uchar SB[4 * 16384];              // 64 KB: ring-4, A 8KB + B 8KB
    float* Cs = reinterpret_cast<float*>(SB);    // epilogue alias (33.8 KB)

    const int tid = threadIdx.x;
    const int lane = tid & 63, wid = tid >> 6;

    // XCD swizzle: 512 blocks, xcd = bid&7 gets 8 bm panels x all 8 bn
    const int bid = blockIdx.x;
    const int swz = (bid & 7) * 64 + (bid >> 3);
    const int bm = swz >> 3, bn = swz & 7;

    const int wm = wid >> 1, wn = wid & 1;

    f32x16 acc[2][2] = {};

    // ---- staging: thread t -> row t>>2 (0..63), 16B unit t&3 (linear dest);
    //      global source unit pre-swizzled by ((t>>3)&3) = (row>>1)&3
    const int srow = tid >> 2;
    const int scol = ((tid & 3) ^ ((tid >> 3) & 3)) * 16;     // bytes
    const uchar* Ag = A + (size_t)(bm * BM + srow) * DIM + scol;
    const uchar* Bg = B + (size_t)(bn * BN + srow) * DIM + scol;
    const int oA = tid * 16;                  // bytes; rows 0..63
    const int oB = 8192 + tid * 16;

    // ---- fragment read offsets (swizzled) ----
    const int xorv = (lane >> 1) & 3;
    const int u0 = ((lane >> 5) * 2) ^ xorv;  // 16B unit of k-bytes [kg*32,+16)
    const int u1 = u0 ^ 1;                    // k-bytes [kg*32+16,+16)
    const int aBase = (wm * 64 + (lane & 31)) * 64;
    const int bBase = 8192 + (wn * 64 + (lane & 31)) * 64;

#define STAGE(bi, kt) do {                                           \
        uchar* sb_ = SB + (bi) * 16384;                              \
        const uchar* a_ = Ag + (size_t)(kt) * BK;                    \
        const uchar* b_ = Bg + (size_t)(kt) * BK;                    \
        GLOAD_LDS16(a_,            sb_ + oA);                        \
        GLOAD_LDS16(a_ + 64 * DIM, sb_ + oA + 4096);                 \
        GLOAD_LDS16(b_,            sb_ + oB);                        \
        GLOAD_LDS16(b_ + 64 * DIM, sb_ + oB + 4096);                 \
    } while (0)

#define LD8(dst, base) do {                                          \
        const i32x4 lo_ = *reinterpret_cast<const i32x4*>(sb_ + (base) + u0 * 16); \
        const i32x4 hi_ = *reinterpret_cast<const i32x4*>(sb_ + (base) + u1 * 16); \
        dst = (i32x8){lo_[0], lo_[1], lo_[2], lo_[3],                \
                      hi_[0], hi_[1], hi_[2], hi_[3]};               \
    } while (0)

#define COMP(bi) do {                                                \
        const uchar* sb_ = SB + (bi) * 16384;                        \
        i32x8 a0, a1, b0, b1;                                        \
        LD8(a0, aBase);                                              \
        LD8(a1, aBase + 2048);                                       \
        LD8(b0, bBase);                                              \
        LD8(b1, bBase + 2048);                                       \
        acc[0][0] = __builtin_amdgcn_mfma_scale_f32_32x32x64_f8f6f4( \
            a0, b0, acc[0][0], 0, 0, 0, 0x7F7F7F7F, 0, 0x7F7F7F7F);  \
        acc[0][1] = __builtin_amdgcn_mfma_scale_f32_32x32x64_f8f6f4( \
            a0, b1, acc[0][1], 0, 0, 0, 0x7F7F7F7F, 0, 0x7F7F7F7F);  \
        acc[1][0] = __builtin_amdgcn_mfma_scale_f32_32x32x64_f8f6f4( \
            a1, b0, acc[1][0], 0, 0, 0, 0x7F7F7F7F, 0, 0x7F7F7F7F);  \
        acc[1][1] = __builtin_amdgcn_mfma_scale_f32_32x32x64_f8f6f4( \
            a1, b1, acc[1][1], 0, 0, 0, 0x7F7F7F7F, 0, 0x7F7F7F7F);  \
    } while (0)

#define W8v asm volatile("s_waitcnt vmcnt(8)" ::: "memory")
#define W4v asm volatile("s_waitcnt vmcnt(4)" ::: "memory")
#define W0v asm volatile("s_waitcnt vmcnt(0)" ::: "memory")
#define BAR __builtin_amdgcn_s_barrier()

    STAGE(0, 0);
    STAGE(1, 1);
    #pragma unroll 1
    for (int k4 = 0; k4 < 12; k4 += 4) {
        STAGE(2, k4 + 2); W8v; BAR; COMP(0);
        STAGE(3, k4 + 3); W8v; BAR; COMP(1);
        STAGE(0, k4 + 4); W8v; BAR; COMP(2);
        STAGE(1, k4 + 5); W8v; BAR; COMP(3);
    }
    STAGE(2, 14); W8v; BAR; COMP(0);   // kt=12
    STAGE(3, 15); W8v; BAR; COMP(1);   // kt=13
    W4v; BAR; COMP(2);                 // kt=14
    W0v; BAR; COMP(3);                 // kt=15
    __syncthreads();

#undef STAGE
#undef LD8
#undef COMP
#undef W8v
#undef W4v
#undef W0v
#undef BAR

    // ---- fused epilogue: out = x + (C + spline(x*r*nw)) * gamma ----
    const int colg = bn * BN + (tid & 31) * 4;   // 4 consecutive output cols
    float sf[20];
    {
        const float4* swp = reinterpret_cast<const float4*>(sw + (size_t)colg * 5);
        #pragma unroll
        for (int q = 0; q < 5; ++q) {
            const float4 w4 = swp[q];
            sf[q * 4 + 0] = w4.x; sf[q * 4 + 1] = w4.y;
            sf[q * 4 + 2] = w4.z; sf[q * 4 + 3] = w4.w;
        }
    }
    const float4 gv  = *reinterpret_cast<const float4*>(gamma + colg);
    const float4 nwv = *reinterpret_cast<const float4*>(nw + colg);

    #pragma unroll
    for (int c = 0; c < 2; ++c) {
        if (wm == c) {
            // C/D 32x32 layout: col=lane&31, row=(r&3)+8*(r>>2)+4*(lane>>5)
            #pragma unroll
            for (int i = 0; i < 2; ++i)
                #pragma unroll
                for (int j = 0; j < 2; ++j)
                    #pragma unroll
                    for (int r = 0; r < 16; ++r) {
                        const int lr = i * 32 + (r & 3) + 8 * (r >> 2) + 4 * (lane >> 5);
                        const int cc = wn * 64 + j * 32 + (lane & 31);
                        Cs[lr * 132 + cc] = acc[i][j][r];
                    }
        }
        __syncthreads();

        #pragma unroll
        for (int v = 0; v < 8; ++v) {
            const int lr = (tid >> 5) * 8 + v;       // 0..63
            const size_t grow = (size_t)(bm * BM + c * 64 + lr);
            const f32x4 cv = *reinterpret_cast<const f32x4*>(&Cs[lr * 132 + (tid & 31) * 4]);
            const float4 xv = *reinterpret_cast<const float4*>(x + grow * DIM + colg);
            const float rv = rrow[grow];
            float4 ov;
            ov.x = xv.x + (cv[0] + spline_eval(xv.x * rv * nwv.x, sf[0],  sf[1],  sf[2],  sf[3],  sf[4]))  * gv.x;
            ov.y = xv.y + (cv[1] + spline_eval(xv.y * rv * nwv.y, sf[5],  sf[6],  sf[7],  sf[8],  sf[9]))  * gv.y;
            ov.z = xv.z + (cv[2] + spline_eval(xv.z * rv * nwv.z, sf[10], sf[11], sf[12], sf[13], sf[14])) * gv.z;
            ov.w = xv.w + (cv[3] + spline_eval(xv.w * rv * nwv.w, sf[15], sf[16], sf[17], sf[18], sf[19])) * gv.w;
            *reinterpret_cast<float4*>(out + grow * DIM + colg) = ov;
        }
        if (c == 0) __syncthreads();
    }
}

// ---------------------------------------------------------------------------
extern "C" void kernel_launch(void* const* d_in, const int* in_sizes, int n_in,
                              void* d_out, int out_size, void* d_ws, size_t ws_size,
                              hipStream_t stream) {
    const float* x     = (const float*)d_in[0];
    const float* nw    = (const float*)d_in[1];
    const float* W     = (const float*)d_in[2];
    const float* sw    = (const float*)d_in[3];
    const float* gamma = (const float*)d_in[4];
    float* out = (float*)d_out;

    uchar* xn8 = (uchar*)d_ws;                                // 8 MB fp8 x_norm
    uchar* W8  = xn8 + (size_t)NTOK * DIM;                    // 1 MB fp8 W
    float* rr  = (float*)(W8 + (size_t)DIM * DIM);            // 32 KB row rsqrt

    prep_kernel<<<dim3(NTOK + DIM), 256, 0, stream>>>(x, nw, W, xn8, W8, rr);
    gemm_ep_kernel<<<dim3((NTOK / BM) * (DIM / BN)), 256, 0, stream>>>(
        xn8, W8, x, rr, nw, sw, gamma, out);
}